// Round 4
// baseline (580.964 us; speedup 1.0000x reference)
//
#include <hip/hip_runtime.h>

// Correlation / cost-volume, fp32.
// corr[b, dy*9+dx, y, x] = (1/128) * sum_c in1[b,c,y,x] * in2[b,c,y+dy-4,x+dx-4]
//
// R4: in2 staged in double-buffered LDS (chunk k+1's global loads issued
// BEFORE computing chunk k -> HBM latency hidden under compute even at
// 1 block/CU). in1 from global (read once; 4 dy-groups/wave dedupe in L1).
// Thread = (ly:4, dy:9, xg:16): one dy, 9 dx, 8 px as split halves at
// x0=4*xg and x0+64 -> 16B-lane-stride LDS reads (R1-measured conflict-free).
// Per thread-channel: 6 ds_read_b128 + 2 global dwordx4 -> 72 FMAs.

#define MAXD 4
#define ND 9
#define NDISP 81
#define BATCH 8
#define CH 128
#define HH 128
#define WW 128
#define HW (HH * WW)
#define CC 4                    // channels per chunk
#define NCHUNK (CH / CC)        // 32
#define TY 4
#define NROW (TY + 2 * MAXD)    // 12 staged rows
#define PITCH 136               // 128 + 4 halo each side
#define NQ 34                   // float4 quads per staged row
#define NSTG (CC * NROW * NQ)   // 1632 quads per chunk
#define NT 576                  // 9 waves

__global__ __launch_bounds__(NT, 2) void corr_kernel(
    const float* __restrict__ in1,
    const float* __restrict__ in2,
    float* __restrict__ out)
{
    __shared__ float s2[2][CC * NROW * PITCH];   // 2 x 26112 B = 52224 B

    const int tid = threadIdx.x;
    const int b   = blockIdx.x;
    const int y0  = blockIdx.y * TY;

    const int ly = tid / (ND * 16);     // 0..3
    const int dy = (tid / 16) % ND;     // 0..8
    const int xg = tid & 15;            // 0..15
    const int x0 = xg * 4;              // half A px; half B at x0+64
    const int rl = ly + dy;             // staged row index

    const float* in1b = in1 + (size_t)b * CH * HW;
    const float* in2b = in2 + (size_t)b * CH * HW;

    // ---- staging slot precompute (3 slots/thread, 1632 quads/chunk) ----
    size_t goff[3]; int loff[3]; bool ok[3], wr[3];
    #pragma unroll
    for (int it = 0; it < 3; ++it) {
        int j   = tid + it * NT;
        wr[it]  = j < NSTG;
        int jj  = wr[it] ? j : 0;
        int c   = jj / (NROW * NQ);
        int rem = jj - c * (NROW * NQ);
        int row = rem / NQ;
        int q   = rem - row * NQ;
        int r   = y0 + row - MAXD;
        int gx  = q * 4 - MAXD;          // quad is fully in/out (halo==4)
        ok[it]  = wr[it] && (r >= 0) && (r < HH) && (gx >= 0) && (gx < WW);
        goff[it] = ok[it] ? ((size_t)c * HW + (size_t)r * WW + gx) : 0;
        loff[it] = (c * NROW + row) * PITCH + q * 4;
    }

    float acc[ND][8];
    #pragma unroll
    for (int d = 0; d < ND; ++d)
        #pragma unroll
        for (int i = 0; i < 8; ++i) acc[d][i] = 0.0f;

    const float4 z4 = make_float4(0.0f, 0.0f, 0.0f, 0.0f);

    // ---- prologue: stage chunk 0 into buffer 0 ----
    float4 stv[3];
    #pragma unroll
    for (int it = 0; it < 3; ++it)
        stv[it] = ok[it] ? *(const float4*)(in2b + goff[it]) : z4;
    #pragma unroll
    for (int it = 0; it < 3; ++it)
        if (wr[it]) *(float4*)&s2[0][loff[it]] = stv[it];
    __syncthreads();

    int p = 0;
    #pragma unroll 1
    for (int k = 0; k < NCHUNK; ++k) {
        const int c0 = k * CC;

        // in1 for this chunk (issued first: needed soonest)
        float4 aA[CC], aB[CC];
        #pragma unroll
        for (int c = 0; c < CC; ++c) {
            const float* p1 = in1b + (size_t)(c0 + c) * HW + (y0 + ly) * WW;
            aA[c] = *(const float4*)(p1 + x0);
            aB[c] = *(const float4*)(p1 + x0 + 64);
        }

        // issue chunk k+1 staging loads (consumed after the barrier ->
        // latency ages across the whole compute phase)
        if (k + 1 < NCHUNK) {
            const float* nb = in2b + (size_t)(k + 1) * CC * HW;
            #pragma unroll
            for (int it = 0; it < 3; ++it)
                stv[it] = ok[it] ? *(const float4*)(nb + goff[it]) : z4;
        }

        // ---- compute chunk k from buffer p ----
        const float* bufp = s2[p];
        #pragma unroll
        for (int c = 0; c < CC; ++c) {
            const float* sr = bufp + (c * NROW + rl) * PITCH + x0;
            float4 w0 = *(const float4*)(sr);
            float4 w1 = *(const float4*)(sr + 4);
            float4 w2 = *(const float4*)(sr + 8);
            float4 w3 = *(const float4*)(sr + 64);
            float4 w4 = *(const float4*)(sr + 68);
            float4 w5 = *(const float4*)(sr + 72);
            float wa[12] = {w0.x, w0.y, w0.z, w0.w,
                            w1.x, w1.y, w1.z, w1.w,
                            w2.x, w2.y, w2.z, w2.w};
            float wb[12] = {w3.x, w3.y, w3.z, w3.w,
                            w4.x, w4.y, w4.z, w4.w,
                            w5.x, w5.y, w5.z, w5.w};
            float a0[4] = {aA[c].x, aA[c].y, aA[c].z, aA[c].w};
            float a1[4] = {aB[c].x, aB[c].y, aB[c].z, aB[c].w};

            #pragma unroll
            for (int d = 0; d < ND; ++d)
                #pragma unroll
                for (int i = 0; i < 4; ++i) {
                    acc[d][i]     = fmaf(a0[i], wa[i + d], acc[d][i]);
                    acc[d][4 + i] = fmaf(a1[i], wb[i + d], acc[d][4 + i]);
                }
        }
        __syncthreads();   // everyone done reading buffer p

        if (k + 1 < NCHUNK) {
            #pragma unroll
            for (int it = 0; it < 3; ++it)
                if (wr[it]) *(float4*)&s2[1 - p][loff[it]] = stv[it];
            p ^= 1;
        }
        __syncthreads();   // writes visible before next compute
    }

    // ---- epilogue: mean over C, coalesced float4 stores ----
    const float scale = 1.0f / (float)CH;
    float* outb = out + (size_t)b * NDISP * HW + (size_t)(y0 + ly) * WW;
    #pragma unroll
    for (int d = 0; d < ND; ++d) {
        float* op = outb + (size_t)(dy * ND + d) * HW;
        float4 v0 = make_float4(acc[d][0] * scale, acc[d][1] * scale,
                                acc[d][2] * scale, acc[d][3] * scale);
        float4 v1 = make_float4(acc[d][4] * scale, acc[d][5] * scale,
                                acc[d][6] * scale, acc[d][7] * scale);
        *(float4*)(op + x0)      = v0;
        *(float4*)(op + x0 + 64) = v1;
    }
}

extern "C" void kernel_launch(void* const* d_in, const int* in_sizes, int n_in,
                              void* d_out, int out_size, void* d_ws, size_t ws_size,
                              hipStream_t stream) {
    const float* in1 = (const float*)d_in[0];
    const float* in2 = (const float*)d_in[1];
    float* out = (float*)d_out;
    dim3 grid(BATCH, HH / TY);
    corr_kernel<<<grid, NT, 0, stream>>>(in1, in2, out);
}

// Round 5
// 220.451 us; speedup vs baseline: 2.6353x; 2.6353x over previous
//
#include <hip/hip_runtime.h>

// Correlation / cost-volume, fp32.
// corr[b, dy*9+dx, y, x] = (1/128) * sum_c in1[b,c,y,x] * in2[b,c,y+dy-4,x+dx-4]
//
// R5: in2 double-buffered in LDS via global_load_lds DMA (no dest VGPRs ->
// register allocator cannot defeat the prefetch; m97 mechanism). Lane owns
// 8 contiguous px; the 16-lane DPP row spans the full 128-px image row, so
// x-halos come from neighbor lanes (v_mov_dpp row_shr/shl, bound_ctrl=0
// gives exact zero-padding at image x-edges). y-padding: DMA clamps OOB
// rows (garbage OK), consumer thread scales its output by 0.
// Per thread-channel: 2 ds_read_b128 + 2 global dwordx4 + 8 DPP -> 72 FMA.
// One barrier per chunk; chunk k+1 DMA issued before computing chunk k.

#define MAXD 4
#define ND 9
#define NDISP 81
#define BATCH 8
#define CH 128
#define HH 128
#define WW 128
#define HW (HH * WW)
#define CC 4                     // channels per chunk
#define NCHUNK (CH / CC)         // 32
#define TY 4
#define NROW (TY + 2 * MAXD)     // 12 staged rows
#define PITCH 132                // 128 + 4 pad floats (bank spread + DMA math)
#define CPC (NROW * PITCH)       // 1584 floats per channel
#define CHF (CC * CPC)           // 6336 floats per chunk
#define CHFP 6400                // padded to 25 * 256
#define NSLOT 25                 // 1-KB DMA slots per chunk
#define NT 576                   // (ly:4)(dy:9)(xg:16) = 9 waves

typedef const __attribute__((address_space(1))) float GAS;
typedef __attribute__((address_space(3))) float LAS;

__device__ __forceinline__ void dma16(const float* g, float* l) {
    __builtin_amdgcn_global_load_lds((GAS*)g, (LAS*)l, 16, 0, 0);
}
__device__ __forceinline__ float dpp_shr1(float x) {   // lane i <- lane i-1
    return __int_as_float(__builtin_amdgcn_update_dpp(
        0, __float_as_int(x), 0x111, 0xF, 0xF, true));
}
__device__ __forceinline__ float dpp_shl1(float x) {   // lane i <- lane i+1
    return __int_as_float(__builtin_amdgcn_update_dpp(
        0, __float_as_int(x), 0x101, 0xF, 0xF, true));
}

__global__ __launch_bounds__(NT, 1) void corr_kernel(
    const float* __restrict__ in1,
    const float* __restrict__ in2,
    float* __restrict__ out)
{
    __shared__ float s2[2][CHFP];   // 2 x 25600 B = 51200 B

    const int tid = threadIdx.x;
    const int b   = blockIdx.x;
    const int y0  = blockIdx.y * TY;

    const int xg   = tid & 15;          // 16 lanes span the full 128-px row
    const int dy   = (tid >> 4) % ND;
    const int ly   = tid / (ND * 16);
    const int lane = tid & 63;
    const int rl   = ly + dy;           // staged row this thread consumes
    const bool rok = (unsigned)(y0 + rl - MAXD) < (unsigned)HH;

    const float* in2b = in2 + (size_t)b * CH * HW;

    // ---- DMA slot precompute: 25 slots x 1 KB, 3 slots/wave ----
    // Chunk LDS layout: [c][row][132]; flat float F = s*256 + 4*lane.
    const int wv = __builtin_amdgcn_readfirstlane(tid >> 6);   // 0..8
    const float* gsrc[3];
    int lds_off[3];
    bool use[3];
    #pragma unroll
    for (int it = 0; it < 3; ++it) {
        int s   = wv + it * 9;
        use[it] = (s < NSLOT);
        int ss  = use[it] ? s : 0;
        int F   = ss * 256 + lane * 4;
        int c   = F / CPC;
        int f   = F - c * CPC;
        int R   = f / PITCH;
        int j   = f - R * PITCH;        // multiple of 4; 128 => pad column
        bool v  = (c < CC) && (j < WW);
        int rr  = y0 - MAXD + R;
        int srow = rr < 0 ? 0 : (rr >= HH ? HH - 1 : rr);  // clamp (garbage OK)
        gsrc[it]   = in2b + (v ? ((size_t)c * HW + (size_t)srow * WW + j) : 0);
        lds_off[it] = ss * 256;
    }

    float acc[ND][8];
    #pragma unroll
    for (int d = 0; d < ND; ++d)
        #pragma unroll
        for (int i = 0; i < 8; ++i) acc[d][i] = 0.0f;

    const float* ap = in1 + (size_t)b * CH * HW + (size_t)(y0 + ly) * WW + xg * 8;

    // ---- prologue: DMA chunk 0 into buffer 0 ----
    #pragma unroll
    for (int it = 0; it < 3; ++it)
        if (use[it]) dma16(gsrc[it], &s2[0][lds_off[it]]);
    #pragma unroll
    for (int it = 0; it < 3; ++it) gsrc[it] += CC * HW;
    __syncthreads();

    #pragma unroll 1
    for (int k = 0; k < NCHUNK; ++k) {
        const int p = k & 1;

        // DMA chunk k+1 into the other buffer (in flight during compute)
        if (k + 1 < NCHUNK) {
            #pragma unroll
            for (int it = 0; it < 3; ++it)
                if (use[it]) dma16(gsrc[it], &s2[1 - p][lds_off[it]]);
            #pragma unroll
            for (int it = 0; it < 3; ++it) gsrc[it] += CC * HW;
        }

        // ---- compute chunk k ----
        #pragma unroll
        for (int cc = 0; cc < CC; ++cc) {
            const float* sp = &s2[p][cc * CPC + rl * PITCH + xg * 8];
            float4 wlo = *(const float4*)(sp);
            float4 whi = *(const float4*)(sp + 4);
            float w[8] = {wlo.x, wlo.y, wlo.z, wlo.w,
                          whi.x, whi.y, whi.z, whi.w};

            float W[16];
            W[0]  = dpp_shr1(w[4]);   // in2[x0-4] from lane-1 (0 at image edge)
            W[1]  = dpp_shr1(w[5]);
            W[2]  = dpp_shr1(w[6]);
            W[3]  = dpp_shr1(w[7]);
            #pragma unroll
            for (int i = 0; i < 8; ++i) W[4 + i] = w[i];
            W[12] = dpp_shl1(w[0]);   // in2[x0+8] from lane+1 (0 at image edge)
            W[13] = dpp_shl1(w[1]);
            W[14] = dpp_shl1(w[2]);
            W[15] = dpp_shl1(w[3]);

            const float* p1 = ap + (size_t)cc * HW;
            float4 a0 = *(const float4*)(p1);
            float4 a1 = *(const float4*)(p1 + 4);
            float a[8] = {a0.x, a0.y, a0.z, a0.w, a1.x, a1.y, a1.z, a1.w};

            #pragma unroll
            for (int d = 0; d < ND; ++d)
                #pragma unroll
                for (int i = 0; i < 8; ++i)
                    acc[d][i] = fmaf(a[i], W[i + d], acc[d][i]);
        }
        ap += CC * HW;
        __syncthreads();
    }

    // ---- epilogue: mean over C; rok==false rows emit exact zeros ----
    const float sc = rok ? (1.0f / (float)CH) : 0.0f;
    float* outb = out + (size_t)b * NDISP * HW + (size_t)(y0 + ly) * WW + xg * 8;
    #pragma unroll
    for (int d = 0; d < ND; ++d) {
        float* op = outb + (size_t)(dy * ND + d) * HW;
        float4 v0 = make_float4(acc[d][0] * sc, acc[d][1] * sc,
                                acc[d][2] * sc, acc[d][3] * sc);
        float4 v1 = make_float4(acc[d][4] * sc, acc[d][5] * sc,
                                acc[d][6] * sc, acc[d][7] * sc);
        *(float4*)(op)     = v0;
        *(float4*)(op + 4) = v1;
    }
}

extern "C" void kernel_launch(void* const* d_in, const int* in_sizes, int n_in,
                              void* d_out, int out_size, void* d_ws, size_t ws_size,
                              hipStream_t stream) {
    const float* in1 = (const float*)d_in[0];
    const float* in2 = (const float*)d_in[1];
    float* out = (float*)d_out;
    dim3 grid(BATCH, HH / TY);
    corr_kernel<<<grid, NT, 0, stream>>>(in1, in2, out);
}